// Round 6
// baseline (296.449 us; speedup 1.0000x reference)
//
#include <hip/hip_runtime.h>
#include <hip/hip_bf16.h>
#include <stdint.h>

#define N_NODES 262144
#define NUM_C   256
#define DIM     128
#define NUM_G   128
#define GMAX    4
#define WPAD    136            // padded LDS row stride for W (shorts)
#define CHUNK   64             // nodes per x-tile chunk
#define NCHUNK  16             // chunks per block
#define BNODES  (CHUNK * NCHUNK)   // 1024 nodes per block

typedef short  bf16x8 __attribute__((ext_vector_type(8)));
typedef float  f32x4  __attribute__((ext_vector_type(4)));
typedef __attribute__((address_space(1))) const void gas_void;
typedef __attribute__((address_space(3))) void       las_void;

__device__ __forceinline__ short f2b(float f) {
    __hip_bfloat16 h = __float2bfloat16(f);
    return *reinterpret_cast<short*>(&h);
}

// async 1 KB global->LDS DMA: lane-linear, zero VGPRs held, tracked by vmcnt
__device__ __forceinline__ void async_copy_1k(const float* g, float* l) {
    __builtin_amdgcn_global_load_lds((gas_void*)g, (las_void*)l, 16, 0, 0);
}

// ---------------------------------------------------------------------------
// Prep: zero out, convert W fp32->bf16, compute c_sq, build cum_end[g] from
// the sorted batch. Grid: 128 x 256. (verified r1-r5)
// ---------------------------------------------------------------------------
__global__ void centroid_prep(const float* __restrict__ W,
                              const int* __restrict__ batch,
                              float* __restrict__ out,
                              short* __restrict__ Wb,
                              float* __restrict__ csq,
                              int* __restrict__ cum_end)
{
    const int t   = threadIdx.x;
    const int b   = blockIdx.x;
    const int gid = b * 256 + t;

    float w = W[gid];
    out[gid] = 0.f;
    Wb[gid] = f2b(w);

    __shared__ float red[256];
    red[t] = w * w;
    __syncthreads();
    for (int off = 64; off > 0; off >>= 1) {
        if ((t & 127) < off) red[t] += red[t + off];
        __syncthreads();
    }
    if (t == 0)   csq[2 * b]     = red[0];
    if (t == 128) csq[2 * b + 1] = red[128];

    long i0 = (long)gid * 8;
    int g = batch[i0];
    if (gid == 0) {
        for (int gg = 0; gg < g; ++gg) cum_end[gg] = 0;
    }
    for (int k = 0; k < 8; ++k) {
        long i = i0 + k;
        int gn = (i + 1 < N_NODES) ? batch[i + 1] : NUM_G;
        if (gn != g) {
            for (int gg = g; gg < gn; ++gg) cum_end[gg] = (int)(i + 1);
        }
        g = gn;
    }
}

// ---------------------------------------------------------------------------
// Main: 256 blocks x 512 threads, 1 block/CU (LDS 144 KB). Block = 1024
// nodes in 16 chunks of 64; x-tiles double-buffered in LDS, filled by async
// global_load_lds DMA (continuous issue -> high MLP, zero VGPR cost).
// Pipeline invariant: chunk j+2's loads are issued AFTER the barrier ending
// chunk j, so each barrier's implicit vmcnt(0) only drains loads that had a
// full compute phase in flight. Wave = one 16-node subtile x one c-half;
// W (bf16) in padded LDS (proven r3/r5); fire-and-forget LDS atomics (r4).
// ---------------------------------------------------------------------------
__global__ __launch_bounds__(512, 2) void centroid_main(
    const float* __restrict__ x,
    const int* __restrict__ batch,
    const short* __restrict__ Wb,
    const float* __restrict__ csq,
    float* __restrict__ out)
{
    __shared__ short wlds[NUM_C * WPAD];        // 69632 B
    __shared__ float xtile[2][CHUNK * DIM];     // 65536 B
    __shared__ float lacc[GMAX * NUM_C];        //  4096 B
    __shared__ float csq_l[NUM_C];              //  1024 B
    __shared__ int   lbatch[BNODES];            //  4096 B  => 144384 total

    const int t  = threadIdx.x;
    const int bb = blockIdx.x * BNODES;

    // ---- stage W (bf16) into padded LDS, coalesced (as r3/r5) ----
#pragma unroll
    for (int i = 0; i < 8; ++i) {
        int k = i * 512 + t;
        bf16x8 v = *(const bf16x8*)(Wb + k * 8);
        *(bf16x8*)(wlds + (k >> 4) * WPAD + (k & 15) * 8) = v;
    }
    if (t < NUM_C) csq_l[t] = csq[t];
    for (int i = t; i < GMAX * NUM_C; i += 512) lacc[i] = 0.f;
    lbatch[t]       = batch[bb + t];
    lbatch[t + 512] = batch[bb + 512 + t];

    const int lane  = t & 63;
    const int wv    = t >> 6;            // 0..7
    const int m16   = lane & 15;
    const int quad  = lane >> 4;
    const int s16   = (wv & 3) * 16;     // subtile base within chunk
    const int cbase = (wv >> 2) * 128;   // c-half base

    // ---- async stage chunk 0; barrier drains it + W/lbatch staging ----
    {
        const float* g0p = x + (size_t)bb * DIM;
#pragma unroll
        for (int i = 0; i < 4; ++i) {
            int k = wv * 4 + i;
            async_copy_1k(g0p + k * 256 + lane * 4, xtile[0] + k * 256);
        }
    }
    __syncthreads();

    const int  gmin    = lbatch[0];
    const int  span    = lbatch[BNODES - 1] - gmin + 1;
    const bool use_lds = (span <= GMAX);

    // chunk 1 in flight during chunk 0's compute
    {
        const float* g1p = x + (size_t)(bb + CHUNK) * DIM;
#pragma unroll
        for (int i = 0; i < 4; ++i) {
            int k = wv * 4 + i;
            async_copy_1k(g1p + k * 256 + lane * 4, xtile[1] + k * 256);
        }
    }

#pragma unroll 1
    for (int j = 0; j < NCHUNK; ++j) {
        const float* xb = xtile[j & 1];

        // ---- A-fragments from LDS x-tile (fp32) + cvt + |x|^2 ----
        const float* ap = xb + (s16 + m16) * DIM + quad * 8;
        bf16x8 a[4];
        float  ss = 0.f;
#pragma unroll
        for (int ks = 0; ks < 4; ++ks) {
            f32x4 u0 = *(const f32x4*)(ap + ks * 32);
            f32x4 u1 = *(const f32x4*)(ap + ks * 32 + 4);
            bf16x8 av;
#pragma unroll
            for (int jj = 0; jj < 4; ++jj) {
                ss += u0[jj] * u0[jj] + u1[jj] * u1[jj];
                av[jj]     = f2b(u0[jj]);
                av[jj + 4] = f2b(u1[jj]);
            }
            a[ks] = av;
        }
        ss += __shfl_xor(ss, 16);
        ss += __shfl_xor(ss, 32);
        float pre[4];
#pragma unroll
        for (int r = 0; r < 4; ++r) pre[r] = __shfl(ss, quad * 4 + r);

        const int  loc0 = j * CHUNK + s16;
        const int  g0   = lbatch[loc0];
        const bool uni  = (g0 == lbatch[loc0 + 15]);
        float* lrow = &lacc[(g0 - gmin) * NUM_C];

        // ---- ct loop: 8 tiles of 16 centroids (this wave's c-half) ----
#pragma unroll 2
        for (int ct = 0; ct < 8; ++ct) {
            const int c = cbase + ct * 16 + m16;
            const short* wp = wlds + c * WPAD + quad * 8;
            bf16x8 b0 = *(const bf16x8*)(wp);
            bf16x8 b1 = *(const bf16x8*)(wp + 32);
            bf16x8 b2 = *(const bf16x8*)(wp + 64);
            bf16x8 b3 = *(const bf16x8*)(wp + 96);
            const float cs = csq_l[c];

            f32x4 acc = {0.f, 0.f, 0.f, 0.f};
            acc = __builtin_amdgcn_mfma_f32_16x16x32_bf16(a[0], b0, acc, 0, 0, 0);
            acc = __builtin_amdgcn_mfma_f32_16x16x32_bf16(a[1], b1, acc, 0, 0, 0);
            acc = __builtin_amdgcn_mfma_f32_16x16x32_bf16(a[2], b2, acc, 0, 0, 0);
            acc = __builtin_amdgcn_mfma_f32_16x16x32_bf16(a[3], b3, acc, 0, 0, 0);

            if (use_lds && uni) {
                float v = 0.f;
#pragma unroll
                for (int r = 0; r < 4; ++r) {
                    float d2 = __builtin_fmaf(acc[r], -2.f, pre[r] + cs);
                    v += __builtin_amdgcn_sqrtf(__builtin_fmaxf(d2, 0.f));
                }
                atomicAdd(&lrow[c], v);       // fire-and-forget
            } else {
#pragma unroll
                for (int r = 0; r < 4; ++r) {
                    float d2 = __builtin_fmaf(acc[r], -2.f, pre[r] + cs);
                    float d  = __builtin_amdgcn_sqrtf(__builtin_fmaxf(d2, 0.f));
                    int   g  = lbatch[loc0 + quad * 4 + r];
                    if (use_lds) atomicAdd(&lacc[(g - gmin) * NUM_C + c], d);
                    else         atomicAdd(&out[g * NUM_C + c], d);
                }
            }
        }

        // barrier: (a) all waves done reading xtile[j&1]; (b) implicit
        // vmcnt(0) drains chunk j+1 (in flight a full compute phase).
        __syncthreads();

        if (j + 2 < NCHUNK) {
            const float* gp = x + (size_t)(bb + (j + 2) * CHUNK) * DIM;
            float* dst = (float*)xtile[j & 1];
#pragma unroll
            for (int i = 0; i < 4; ++i) {
                int k = wv * 4 + i;
                async_copy_1k(gp + k * 256 + lane * 4, dst + k * 256);
            }
        }
    }

    __syncthreads();
    if (use_lds) {
        for (int i = t; i < span * NUM_C; i += 512)
            atomicAdd(&out[(gmin + (i >> 8)) * NUM_C + (i & 255)], lacc[i]);
    }
}

// ---------------------------------------------------------------------------
// Finish: divide sums by per-graph counts. Grid: 128 x 256.
// ---------------------------------------------------------------------------
__global__ void centroid_finish(float* __restrict__ out,
                                const int* __restrict__ cum_end)
{
    const int g = blockIdx.x;
    const int c = threadIdx.x;
    int cnt = cum_end[g] - (g ? cum_end[g - 1] : 0);
    float denom = (float)(cnt > 0 ? cnt : 1);
    out[g * NUM_C + c] /= denom;
}

extern "C" void kernel_launch(void* const* d_in, const int* in_sizes, int n_in,
                              void* d_out, int out_size, void* d_ws, size_t ws_size,
                              hipStream_t stream) {
    const float* x     = (const float*)d_in[0];
    const int*   batch = (const int*)d_in[1];
    const float* W     = (const float*)d_in[2];
    float*       out   = (float*)d_out;

    // workspace: Wb (64 KB) | csq (1 KB) | cum_end (512 B)
    short* Wb      = (short*)d_ws;
    float* csq     = (float*)((char*)d_ws + 65536);
    int*   cum_end = (int*)((char*)d_ws + 65536 + 1024);

    centroid_prep<<<128, 256, 0, stream>>>(W, batch, out, Wb, csq, cum_end);
    centroid_main<<<N_NODES / BNODES, 512, 0, stream>>>(x, batch, Wb, csq, out);
    centroid_finish<<<NUM_G, 256, 0, stream>>>(out, cum_end);
}

// Round 7
// 264.373 us; speedup vs baseline: 1.1213x; 1.1213x over previous
//
#include <hip/hip_runtime.h>
#include <hip/hip_bf16.h>

#define N_NODES 262144
#define NUM_C   256
#define DIM     128
#define NUM_G   128
#define GMAX    4

typedef short  bf16x8 __attribute__((ext_vector_type(8)));
typedef float  f32x4  __attribute__((ext_vector_type(4)));

__device__ __forceinline__ short f2b(float f) {
    __hip_bfloat16 h = __float2bfloat16(f);
    return *reinterpret_cast<short*>(&h);
}

// ---------------------------------------------------------------------------
// Prep: zero out, convert W fp32->bf16, compute c_sq, build cum_end[g] from
// the sorted batch. Grid: 128 x 256. (verified r1-r6)
// ---------------------------------------------------------------------------
__global__ void centroid_prep(const float* __restrict__ W,
                              const int* __restrict__ batch,
                              float* __restrict__ out,
                              short* __restrict__ Wb,
                              float* __restrict__ csq,
                              int* __restrict__ cum_end)
{
    const int t   = threadIdx.x;
    const int b   = blockIdx.x;
    const int gid = b * 256 + t;

    float w = W[gid];
    out[gid] = 0.f;
    Wb[gid] = f2b(w);

    __shared__ float red[256];
    red[t] = w * w;
    __syncthreads();
    for (int off = 64; off > 0; off >>= 1) {
        if ((t & 127) < off) red[t] += red[t + off];
        __syncthreads();
    }
    if (t == 0)   csq[2 * b]     = red[0];
    if (t == 128) csq[2 * b + 1] = red[128];

    long i0 = (long)gid * 8;
    int g = batch[i0];
    if (gid == 0) {
        for (int gg = 0; gg < g; ++gg) cum_end[gg] = 0;
    }
    for (int k = 0; k < 8; ++k) {
        long i = i0 + k;
        int gn = (i + 1 < N_NODES) ? batch[i + 1] : NUM_G;
        if (gn != g) {
            for (int gg = g; gg < gn; ++gg) cum_end[gg] = (int)(i + 1);
        }
        g = gn;
    }
}

// ---------------------------------------------------------------------------
// Main (r7): 1024 blocks x 256 threads. NO W in LDS -- each wave holds its
// 64 centroids' B-fragments in registers (64 VGPR, loaded once from L2-hot
// bf16 Wb). LDS = 5 KB (lacc + lbatch) -> occupancy is VGPR-bound at
// ~4 waves/SIMD (16 waves/CU), double r3's residency, and the LDS pipe only
// carries 6 shuffles + 4 fire-and-forget atomics per chunk. Block = 256
// nodes; wave = c-quarter x 16 chunks of 16 nodes; A loaded coalesced from
// global per chunk (L1/L2-shared across the 4 waves).
// ---------------------------------------------------------------------------
__global__ __launch_bounds__(256, 4) void centroid_main(
    const float* __restrict__ x,
    const int* __restrict__ batch,
    const short* __restrict__ Wb,
    const float* __restrict__ csq,
    float* __restrict__ out)
{
    __shared__ float lacc[GMAX * NUM_C];   // 4096 B
    __shared__ int   lbatch[256];          // 1024 B

    const int t  = threadIdx.x;
    const int nb = blockIdx.x << 8;        // 256 nodes per block

#pragma unroll
    for (int i = 0; i < GMAX; ++i) lacc[i * 256 + t] = 0.f;
    lbatch[t] = batch[nb + t];

    const int lane  = t & 63;
    const int wv    = t >> 6;              // 0..3 -> c-quarter
    const int m16   = lane & 15;
    const int quad  = lane >> 4;
    const int cbase = wv * 64;

    // ---- B-fragments for this wave's 64 centroids: 64 VGPR, loaded once ----
    bf16x8 B[4][4];
    float  cs[4];
#pragma unroll
    for (int ct = 0; ct < 4; ++ct) {
        const int c = cbase + ct * 16 + m16;
        const short* wp = Wb + c * DIM + quad * 8;
#pragma unroll
        for (int ks = 0; ks < 4; ++ks)
            B[ct][ks] = *(const bf16x8*)(wp + ks * 32);
        cs[ct] = csq[c];
    }

    __syncthreads();                       // lacc / lbatch visible

    const int  gmin    = lbatch[0];
    const int  span    = lbatch[255] - gmin + 1;
    const bool use_lds = (span <= GMAX);

    // ---- 16 chunks of 16 nodes ----
#pragma unroll 1
    for (int j = 0; j < 16; ++j) {
        const int n0 = nb + j * 16;
        const float* ap = x + (size_t)(n0 + m16) * DIM + quad * 8;

        bf16x8 a[4];
        float  ss = 0.f;
#pragma unroll
        for (int ks = 0; ks < 4; ++ks) {
            f32x4 u0 = *(const f32x4*)(ap + ks * 32);
            f32x4 u1 = *(const f32x4*)(ap + ks * 32 + 4);
            bf16x8 av;
#pragma unroll
            for (int jj = 0; jj < 4; ++jj) {
                ss += u0[jj] * u0[jj] + u1[jj] * u1[jj];
                av[jj]     = f2b(u0[jj]);
                av[jj + 4] = f2b(u1[jj]);
            }
            a[ks] = av;
        }
        ss += __shfl_xor(ss, 16);
        ss += __shfl_xor(ss, 32);          // xsq of node n0 + m16
        float pre[4];
#pragma unroll
        for (int r = 0; r < 4; ++r) pre[r] = __shfl(ss, quad * 4 + r);

        const int  l0  = j * 16;
        const int  g0  = lbatch[l0];
        const bool uni = (g0 == lbatch[l0 + 15]);
        float* lrow = &lacc[(g0 - gmin) * NUM_C];

#pragma unroll
        for (int ct = 0; ct < 4; ++ct) {
            f32x4 acc = {0.f, 0.f, 0.f, 0.f};
            acc = __builtin_amdgcn_mfma_f32_16x16x32_bf16(a[0], B[ct][0], acc, 0, 0, 0);
            acc = __builtin_amdgcn_mfma_f32_16x16x32_bf16(a[1], B[ct][1], acc, 0, 0, 0);
            acc = __builtin_amdgcn_mfma_f32_16x16x32_bf16(a[2], B[ct][2], acc, 0, 0, 0);
            acc = __builtin_amdgcn_mfma_f32_16x16x32_bf16(a[3], B[ct][3], acc, 0, 0, 0);

            const int c = cbase + ct * 16 + m16;
            if (use_lds && uni) {
                float v = 0.f;
#pragma unroll
                for (int r = 0; r < 4; ++r) {
                    float d2 = __builtin_fmaf(acc[r], -2.f, pre[r] + cs[ct]);
                    v += __builtin_amdgcn_sqrtf(__builtin_fmaxf(d2, 0.f));
                }
                atomicAdd(&lrow[c], v);    // fire-and-forget, 16 addrs/wave
            } else {
#pragma unroll
                for (int r = 0; r < 4; ++r) {
                    float d2 = __builtin_fmaf(acc[r], -2.f, pre[r] + cs[ct]);
                    float d  = __builtin_amdgcn_sqrtf(__builtin_fmaxf(d2, 0.f));
                    int   g  = lbatch[l0 + quad * 4 + r];
                    if (use_lds) atomicAdd(&lacc[(g - gmin) * NUM_C + c], d);
                    else         atomicAdd(&out[g * NUM_C + c], d);
                }
            }
        }
    }

    __syncthreads();
    if (use_lds) {
        for (int i = t; i < span * NUM_C; i += 256)
            atomicAdd(&out[(gmin + (i >> 8)) * NUM_C + (i & 255)], lacc[i]);
    }
}

// ---------------------------------------------------------------------------
// Finish: divide sums by per-graph counts. Grid: 128 x 256.
// ---------------------------------------------------------------------------
__global__ void centroid_finish(float* __restrict__ out,
                                const int* __restrict__ cum_end)
{
    const int g = blockIdx.x;
    const int c = threadIdx.x;
    int cnt = cum_end[g] - (g ? cum_end[g - 1] : 0);
    float denom = (float)(cnt > 0 ? cnt : 1);
    out[g * NUM_C + c] /= denom;
}

extern "C" void kernel_launch(void* const* d_in, const int* in_sizes, int n_in,
                              void* d_out, int out_size, void* d_ws, size_t ws_size,
                              hipStream_t stream) {
    const float* x     = (const float*)d_in[0];
    const int*   batch = (const int*)d_in[1];
    const float* W     = (const float*)d_in[2];
    float*       out   = (float*)d_out;

    // workspace: Wb (64 KB) | csq (1 KB) | cum_end (512 B)
    short* Wb      = (short*)d_ws;
    float* csq     = (float*)((char*)d_ws + 65536);
    int*   cum_end = (int*)((char*)d_ws + 65536 + 1024);

    centroid_prep<<<128, 256, 0, stream>>>(W, batch, out, Wb, csq, cum_end);
    centroid_main<<<N_NODES / 256, 256, 0, stream>>>(x, batch, Wb, csq, out);
    centroid_finish<<<NUM_G, 256, 0, stream>>>(out, cum_end);
}